// Round 2
// baseline (444.620 us; speedup 1.0000x reference)
//
#include <hip/hip_runtime.h>
#include <math.h>

#define NN 64      // nodes
#define TT 256     // frames
#define FF 13      // input features
#define EE 4032    // edges (complete digraph)
#define PP 128     // pooling channels / GAT1 out
#define HH 128     // hidden

__device__ __forceinline__ float wave_max64(float v) {
#pragma unroll
  for (int off = 32; off > 0; off >>= 1) v = fmaxf(v, __shfl_xor(v, off, 64));
  return v;
}
__device__ __forceinline__ float wave_sum64(float v) {
#pragma unroll
  for (int off = 32; off > 0; off >>= 1) v += __shfl_xor(v, off, 64);
  return v;
}
__device__ __forceinline__ float sigm(float x) { return 1.f / (1.f + __expf(-x)); }
__device__ __forceinline__ float tanh_fast(float x) { return 1.f - 2.f / (__expf(2.f * x) + 1.f); }

// ---------------------------------------------------------------------------
// Per-frame GNN: GAT1 (4 heads) -> relu -> GAT2 (1 head) -> relu ->
// attention-pool + max-pool -> embs[t][256]
// One block per frame, 512 threads (8 waves). Complete-graph edge indexing:
// edge (s->d) has id j = s*63 + (d<s ? d : d-1)  [np.nonzero(~eye) order].
// ---------------------------------------------------------------------------
__global__ __launch_bounds__(512, 2)
void gnn_kernel(const float* __restrict__ x, const float* __restrict__ ea_g,
                const float* __restrict__ W1, const float* __restrict__ a_src1,
                const float* __restrict__ a_dst1, const float* __restrict__ We1,
                const float* __restrict__ a_edge1, const float* __restrict__ b1,
                const float* __restrict__ W2, const float* __restrict__ a_src2,
                const float* __restrict__ a_dst2, const float* __restrict__ We2,
                const float* __restrict__ a_edge2, const float* __restrict__ b2,
                const float* __restrict__ Wg, const float* __restrict__ bg,
                float* __restrict__ embs)
{
  __shared__ float x_s[NN * FF];
  __shared__ float W1_s[FF * PP];
  __shared__ float ea_s[EE];
  __shared__ float hA_s[NN * PP];   // h1 (GAT1 projected), later p2 (GAT2 projected)
  __shared__ float hB_s[NN * PP];   // relu(GAT1 out), later relu(GAT2 out)
  __shared__ float as1_s[NN * 4];
  __shared__ float ad1_s[NN * 4];
  __shared__ float asrc1_s[PP], adst1_s[PP], asrc2_s[PP], adst2_s[PP];
  __shared__ float b1_s[PP], b2_s[PP], Wg_s[PP];
  __shared__ float as2_s[NN], ad2_s[NN];
  __shared__ float coef_s[8 * 64 * 4];
  __shared__ float wed_s[8];
  __shared__ float attn_s[NN];

  const int tid = threadIdx.x;
  const int t = blockIdx.x;
  const int wave = tid >> 6, lane = tid & 63;

  // stage inputs
  for (int i = tid; i < NN * FF; i += 512) x_s[i] = x[t * NN * FF + i];
  for (int i = tid; i < FF * PP; i += 512) W1_s[i] = W1[i];
  for (int i = tid; i < EE; i += 512) ea_s[i] = ea_g[t * EE + i];
  if (tid < PP) {
    asrc1_s[tid] = a_src1[tid]; adst1_s[tid] = a_dst1[tid];
    asrc2_s[tid] = a_src2[tid]; adst2_s[tid] = a_dst2[tid];
    b1_s[tid] = b1[tid]; b2_s[tid] = b2[tid]; Wg_s[tid] = Wg[tid];
  }
  if (tid >= 128 && tid < 132) {   // wedot1[h] = sum_c We1[h,c]*a_edge1[h,c]
    const int h = tid - 128;
    float acc = 0.f;
    for (int c = 0; c < 32; ++c) acc += We1[h * 32 + c] * a_edge1[h * 32 + c];
    wed_s[h] = acc;
  }
  if (tid == 132) {                // wedot2 = dot(We2, a_edge2)
    float acc = 0.f;
    for (int c = 0; c < 128; ++c) acc += We2[c] * a_edge2[c];
    wed_s[4] = acc;
  }
  __syncthreads();

  // h1 = x @ W1  -> hA  (8192 outputs, 16/thread)
  {
    const int c = tid & 127, ib = tid >> 7;
    for (int q = 0; q < 16; ++q) {
      const int i = ib * 16 + q;
      float acc = 0.f;
#pragma unroll
      for (int f = 0; f < FF; ++f) acc += x_s[i * FF + f] * W1_s[f * PP + c];
      hA_s[i * PP + c] = acc;
    }
  }
  __syncthreads();

  // per-node attention dots: as1[i][h], ad1[i][h]
  {
    const int half = tid >> 8;          // 0: src dots, 1: dst dots
    const int tt2 = tid & 255;
    const int i = tt2 >> 2, h = tt2 & 3;
    const float* aw = half ? adst1_s : asrc1_s;
    float acc = 0.f;
    for (int cc = 0; cc < 32; ++cc) {
      const int c = (cc + tid) & 31;    // rotation: LDS bank-conflict-free
      acc += hA_s[i * PP + h * 32 + c] * aw[h * 32 + c];
    }
    if (half) ad1_s[i * 4 + h] = acc; else as1_s[i * 4 + h] = acc;
  }
  __syncthreads();

  // GAT1 aggregation: each wave owns dst d = kk*8+wave; lanes 0..62 = srcs
  for (int kk = 0; kk < 8; ++kk) {
    const int d = kk * 8 + wave;
    {
      float a0, a1, a2, a3;
      if (lane < 63) {
        const int s = lane + (lane >= d ? 1 : 0);
        const int j = s * 63 + (d < s ? d : d - 1);
        const float ev = ea_s[j];
        a0 = as1_s[s * 4 + 0] + ad1_s[d * 4 + 0] + ev * wed_s[0];
        a1 = as1_s[s * 4 + 1] + ad1_s[d * 4 + 1] + ev * wed_s[1];
        a2 = as1_s[s * 4 + 2] + ad1_s[d * 4 + 2] + ev * wed_s[2];
        a3 = as1_s[s * 4 + 3] + ad1_s[d * 4 + 3] + ev * wed_s[3];
        a0 = a0 > 0.f ? a0 : 0.2f * a0;
        a1 = a1 > 0.f ? a1 : 0.2f * a1;
        a2 = a2 > 0.f ? a2 : 0.2f * a2;
        a3 = a3 > 0.f ? a3 : 0.2f * a3;
      } else { a0 = a1 = a2 = a3 = -1e30f; }
      const float m0 = wave_max64(a0), m1 = wave_max64(a1);
      const float m2 = wave_max64(a2), m3 = wave_max64(a3);
      const float p0 = (lane < 63) ? __expf(a0 - m0) : 0.f;
      const float p1 = (lane < 63) ? __expf(a1 - m1) : 0.f;
      const float p2 = (lane < 63) ? __expf(a2 - m2) : 0.f;
      const float p3 = (lane < 63) ? __expf(a3 - m3) : 0.f;
      const float s0 = wave_sum64(p0), s1 = wave_sum64(p1);
      const float s2 = wave_sum64(p2), s3 = wave_sum64(p3);
      float* cw = &coef_s[(wave * 64 + lane) * 4];
      cw[0] = p0 / (s0 + 1e-16f);
      cw[1] = p1 / (s1 + 1e-16f);
      cw[2] = p2 / (s2 + 1e-16f);
      cw[3] = p3 / (s3 + 1e-16f);
    }
    __syncthreads();
    {
      const int c0 = lane * 2;
      const int hh = c0 >> 5;
      float acc0 = 0.f, acc1 = 0.f;
      const float* cf = &coef_s[wave * 64 * 4 + hh];
      for (int s = 0; s < 63; ++s) {
        const int sn = s + (s >= d ? 1 : 0);
        const float cv = cf[s * 4];
        const float2 hv = *(const float2*)&hA_s[sn * PP + c0];
        acc0 += cv * hv.x; acc1 += cv * hv.y;
      }
      hB_s[d * PP + c0]     = fmaxf(acc0 + b1_s[c0], 0.f);
      hB_s[d * PP + c0 + 1] = fmaxf(acc1 + b1_s[c0 + 1], 0.f);
    }
    __syncthreads();
  }

  // p2 = relu(gat1) @ W2 -> hA (reuse; h1 dead).  W2 streamed from L2.
  {
    const int c = tid & 127, ib = tid >> 7;
    float acc[16];
#pragma unroll
    for (int q = 0; q < 16; ++q) acc[q] = 0.f;
    for (int f0 = 0; f0 < 128; f0 += 4) {
      const float w0 = W2[(f0 + 0) * PP + c];
      const float w1 = W2[(f0 + 1) * PP + c];
      const float w2 = W2[(f0 + 2) * PP + c];
      const float w3 = W2[(f0 + 3) * PP + c];
#pragma unroll
      for (int q = 0; q < 16; ++q) {
        const float4 hv = *(const float4*)&hB_s[(ib * 16 + q) * PP + f0];
        acc[q] += hv.x * w0 + hv.y * w1 + hv.z * w2 + hv.w * w3;
      }
    }
#pragma unroll
    for (int q = 0; q < 16; ++q) hA_s[(ib * 16 + q) * PP + c] = acc[q];
  }
  __syncthreads();

  // as2/ad2 node dots
  if (tid < 128) {
    const int i = tid >> 1, sel = tid & 1;
    const float* aw = sel ? adst2_s : asrc2_s;
    float acc = 0.f;
    for (int cc = 0; cc < 128; ++cc) {
      const int c = (cc + tid) & 127;
      acc += hA_s[i * PP + c] * aw[c];
    }
    if (sel) ad2_s[i] = acc; else as2_s[i] = acc;
  }
  __syncthreads();

  // GAT2 aggregation (1 head)
  for (int kk = 0; kk < 8; ++kk) {
    const int d = kk * 8 + wave;
    {
      float a;
      if (lane < 63) {
        const int s = lane + (lane >= d ? 1 : 0);
        const int j = s * 63 + (d < s ? d : d - 1);
        a = as2_s[s] + ad2_s[d] + ea_s[j] * wed_s[4];
        a = a > 0.f ? a : 0.2f * a;
      } else a = -1e30f;
      const float m = wave_max64(a);
      const float p = (lane < 63) ? __expf(a - m) : 0.f;
      const float ssum = wave_sum64(p);
      coef_s[wave * 64 + lane] = p / (ssum + 1e-16f);
    }
    __syncthreads();
    {
      const int c0 = lane * 2;
      float acc0 = 0.f, acc1 = 0.f;
      const float* cf = &coef_s[wave * 64];
      for (int s = 0; s < 63; ++s) {
        const int sn = s + (s >= d ? 1 : 0);
        const float cv = cf[s];
        const float2 hv = *(const float2*)&hA_s[sn * PP + c0];
        acc0 += cv * hv.x; acc1 += cv * hv.y;
      }
      hB_s[d * PP + c0]     = fmaxf(acc0 + b2_s[c0], 0.f);
      hB_s[d * PP + c0 + 1] = fmaxf(acc1 + b2_s[c0 + 1], 0.f);
    }
    __syncthreads();
  }

  // attention pooling (softmax over 64 nodes, wave 0) + max pooling
  if (tid < 64) {
    float acc = 0.f;
    for (int cc = 0; cc < 128; ++cc) {
      const int c = (cc + tid) & 127;
      acc += hB_s[tid * PP + c] * Wg_s[c];
    }
    const float logit = acc + bg[0];
    const float m = wave_max64(logit);
    const float p = __expf(logit - m);
    const float ssum = wave_sum64(p);
    attn_s[tid] = p / ssum;
  }
  __syncthreads();
  if (tid < 128) {
    const int c = tid;
    float acc = 0.f, mx = -1e30f;
    for (int i = 0; i < NN; ++i) {
      const float v = hB_s[i * PP + c];
      acc += attn_s[i] * v;
      mx = fmaxf(mx, v);
    }
    embs[t * 256 + c] = acc;
    embs[t * 256 + 128 + c] = mx;
  }
}

// ---------------------------------------------------------------------------
// Z[t][j] = Wih_f[j,:]·embs[t] + bih_f[j] + bhh_f[j]   (blocks 0..255)
// Zb[j]   = Wih_b[j,:]·embs[255] + bih_b[j] + bhh_b[j] (block 256)
// ---------------------------------------------------------------------------
__global__ __launch_bounds__(512, 2)
void zproj_kernel(const float* __restrict__ embs,
                  const float* __restrict__ Wih_f, const float* __restrict__ bih_f,
                  const float* __restrict__ bhh_f,
                  const float* __restrict__ Wih_b, const float* __restrict__ bih_b,
                  const float* __restrict__ bhh_b,
                  float* __restrict__ Z, float* __restrict__ Zb)
{
  __shared__ float e_s[256];
  const int t = blockIdx.x;
  const int j = threadIdx.x;
  const bool bwd = (t == TT);
  const int tsrc = bwd ? (TT - 1) : t;
  if (j < 256) e_s[j] = embs[tsrc * 256 + j];
  __syncthreads();
  const float* W = bwd ? Wih_b : Wih_f;
  float acc = bwd ? (bih_b[j] + bhh_b[j]) : (bih_f[j] + bhh_f[j]);
  const float4* Wr = (const float4*)(W + j * 256);
  const float4* er = (const float4*)e_s;
#pragma unroll 8
  for (int k = 0; k < 64; ++k) {
    const float4 w = Wr[k];
    const float4 e = er[k];
    acc += w.x * e.x + w.y * e.y + w.z * e.z + w.w * e.w;
  }
  if (bwd) Zb[j] = acc; else Z[t * 512 + j] = acc;
}

// ---------------------------------------------------------------------------
// Forward LSTM recurrence (256 steps, single block).
// Whh row held in 32 NAMED float4 registers (every access compile-time
// constant -> guaranteed VGPR residency; a float w[128] array is runtime-
// indexed at SROA time and goes to scratch -- that was the 283us bug).
// 4 independent accumulators cut the FMA dependency chain 128 -> 32 deep.
// ---------------------------------------------------------------------------
#define RPT32(M) M(0)M(1)M(2)M(3)M(4)M(5)M(6)M(7)M(8)M(9)M(10)M(11)M(12)M(13)M(14)M(15)M(16)M(17)M(18)M(19)M(20)M(21)M(22)M(23)M(24)M(25)M(26)M(27)M(28)M(29)M(30)M(31)

__global__ __launch_bounds__(512, 2)
void lstm_kernel(const float* __restrict__ Z, const float* __restrict__ Zb,
                 const float* __restrict__ Whh_f,
                 const float* __restrict__ Wo, const float* __restrict__ bo,
                 float* __restrict__ out)
{
  __shared__ float h_s[128];
  __shared__ float g_s[512];
  __shared__ float hb_s[128];
  __shared__ float red_s[8];
  const int j = threadIdx.x;

  const float4* __restrict__ Wr = (const float4*)(Whh_f + j * 128);
#define DECLW(k) float4 w##k = Wr[k];
  RPT32(DECLW)
#undef DECLW

  float c = 0.f;
  if (j < 128) h_s[j] = 0.f;
  __syncthreads();

  float zcur = Z[j];
  const float4* hr = (const float4*)h_s;
  for (int t = 0; t < TT; ++t) {
    const float znext = (t < TT - 1) ? Z[(t + 1) * 512 + j] : 0.f;  // prefetch
    float a0 = zcur, a1 = 0.f, a2 = 0.f, a3 = 0.f;
#define ACCK(k, A) { const float4 hv = hr[k]; \
    A = fmaf(hv.x, w##k.x, A); A = fmaf(hv.y, w##k.y, A); \
    A = fmaf(hv.z, w##k.z, A); A = fmaf(hv.w, w##k.w, A); }
    ACCK(0, a0)  ACCK(1, a1)  ACCK(2, a2)  ACCK(3, a3)
    ACCK(4, a0)  ACCK(5, a1)  ACCK(6, a2)  ACCK(7, a3)
    ACCK(8, a0)  ACCK(9, a1)  ACCK(10, a2) ACCK(11, a3)
    ACCK(12, a0) ACCK(13, a1) ACCK(14, a2) ACCK(15, a3)
    ACCK(16, a0) ACCK(17, a1) ACCK(18, a2) ACCK(19, a3)
    ACCK(20, a0) ACCK(21, a1) ACCK(22, a2) ACCK(23, a3)
    ACCK(24, a0) ACCK(25, a1) ACCK(26, a2) ACCK(27, a3)
    ACCK(28, a0) ACCK(29, a1) ACCK(30, a2) ACCK(31, a3)
#undef ACCK
    g_s[j] = (a0 + a1) + (a2 + a3);
    __syncthreads();
    if (j < 128) {
      const float gi = g_s[j], gf = g_s[128 + j], gg = g_s[256 + j], go = g_s[384 + j];
      c = sigm(gf) * c + sigm(gi) * tanh_fast(gg);
      h_s[j] = sigm(go) * tanh_fast(c);
    }
    __syncthreads();
    zcur = znext;
  }

  // backward LSTM, first step only (h=c=0): elementwise on Zb
  if (j < 128) {
    const float gi = Zb[j], gg = Zb[256 + j], go = Zb[384 + j];
    const float cb = sigm(gi) * tanh_fast(gg);
    hb_s[j] = sigm(go) * tanh_fast(cb);
  }
  __syncthreads();

  // out = sigmoid(concat(h_f, h_b) · Wo + bo)
  float v = 0.f;
  if (j < 128) v = h_s[j] * Wo[j];
  else if (j < 256) v = hb_s[j - 128] * Wo[j];
  v = wave_sum64(v);
  if ((j & 63) == 0) red_s[j >> 6] = v;
  __syncthreads();
  if (j == 0) {
    float s = bo[0];
#pragma unroll
    for (int k = 0; k < 8; ++k) s += red_s[k];
    out[0] = 1.f / (1.f + __expf(-s));
  }
}

extern "C" void kernel_launch(void* const* d_in, const int* in_sizes, int n_in,
                              void* d_out, int out_size, void* d_ws, size_t ws_size,
                              hipStream_t stream) {
  const float* x       = (const float*)d_in[0];
  // d_in[1] = edge_index (int32) — complete digraph, indexed analytically
  const float* ea      = (const float*)d_in[2];
  const float* W1      = (const float*)d_in[3];
  const float* a_src1  = (const float*)d_in[4];
  const float* a_dst1  = (const float*)d_in[5];
  const float* We1     = (const float*)d_in[6];
  const float* a_edge1 = (const float*)d_in[7];
  const float* b1      = (const float*)d_in[8];
  const float* W2      = (const float*)d_in[9];
  const float* a_src2  = (const float*)d_in[10];
  const float* a_dst2  = (const float*)d_in[11];
  const float* We2     = (const float*)d_in[12];
  const float* a_edge2 = (const float*)d_in[13];
  const float* b2      = (const float*)d_in[14];
  const float* Wg      = (const float*)d_in[15];
  const float* bg      = (const float*)d_in[16];
  const float* Wih_f   = (const float*)d_in[17];
  const float* Whh_f   = (const float*)d_in[18];
  const float* bih_f   = (const float*)d_in[19];
  const float* bhh_f   = (const float*)d_in[20];
  const float* Wih_b   = (const float*)d_in[21];
  // d_in[22] = Whh_b — unused: backward LSTM contributes only its first step (h=0)
  const float* bih_b   = (const float*)d_in[23];
  const float* bhh_b   = (const float*)d_in[24];
  const float* Wo      = (const float*)d_in[25];
  const float* bo      = (const float*)d_in[26];
  float* out = (float*)d_out;

  float* embs = (float*)d_ws;            // 256*256 floats
  float* Z    = embs + 256 * 256;        // 256*512 floats
  float* Zb   = Z + 256 * 512;           // 512 floats

  gnn_kernel<<<256, 512, 0, stream>>>(x, ea, W1, a_src1, a_dst1, We1, a_edge1, b1,
                                      W2, a_src2, a_dst2, We2, a_edge2, b2, Wg, bg, embs);
  zproj_kernel<<<257, 512, 0, stream>>>(embs, Wih_f, bih_f, bhh_f, Wih_b, bih_b, bhh_b, Z, Zb);
  lstm_kernel<<<1, 512, 0, stream>>>(Z, Zb, Whh_f, Wo, bo, out);
}

// Round 3
// 378.088 us; speedup vs baseline: 1.1760x; 1.1760x over previous
//
#include <hip/hip_runtime.h>
#include <math.h>

#define NN 64      // nodes
#define TT 256     // frames
#define FF 13      // input features
#define EE 4032    // edges (complete digraph)
#define PP 128     // pooling channels / GAT1 out
#define HH 128     // hidden

typedef float f32x4 __attribute__((ext_vector_type(4)));

__device__ __forceinline__ float wave_max64(float v) {
#pragma unroll
  for (int off = 32; off > 0; off >>= 1) v = fmaxf(v, __shfl_xor(v, off, 64));
  return v;
}
__device__ __forceinline__ float wave_sum64(float v) {
#pragma unroll
  for (int off = 32; off > 0; off >>= 1) v += __shfl_xor(v, off, 64);
  return v;
}
__device__ __forceinline__ float sigm(float x) { return 1.f / (1.f + __expf(-x)); }
__device__ __forceinline__ float tanh_fast(float x) { return 1.f - 2.f / (__expf(2.f * x) + 1.f); }

// ---------------------------------------------------------------------------
// Per-frame GNN: GAT1 (4 heads) -> relu -> GAT2 (1 head) -> relu ->
// attention-pool + max-pool -> embs[t][256]
// One block per frame, 512 threads (8 waves). Complete-graph edge indexing:
// edge (s->d) has id j = s*63 + (d<s ? d : d-1)  [np.nonzero(~eye) order].
// ---------------------------------------------------------------------------
__global__ __launch_bounds__(512, 2)
void gnn_kernel(const float* __restrict__ x, const float* __restrict__ ea_g,
                const float* __restrict__ W1, const float* __restrict__ a_src1,
                const float* __restrict__ a_dst1, const float* __restrict__ We1,
                const float* __restrict__ a_edge1, const float* __restrict__ b1,
                const float* __restrict__ W2, const float* __restrict__ a_src2,
                const float* __restrict__ a_dst2, const float* __restrict__ We2,
                const float* __restrict__ a_edge2, const float* __restrict__ b2,
                const float* __restrict__ Wg, const float* __restrict__ bg,
                float* __restrict__ embs)
{
  __shared__ float x_s[NN * FF];
  __shared__ float W1_s[FF * PP];
  __shared__ float ea_s[EE];
  __shared__ float hA_s[NN * PP];   // h1 (GAT1 projected), later p2 (GAT2 projected)
  __shared__ float hB_s[NN * PP];   // relu(GAT1 out), later relu(GAT2 out)
  __shared__ float as1_s[NN * 4];
  __shared__ float ad1_s[NN * 4];
  __shared__ float asrc1_s[PP], adst1_s[PP], asrc2_s[PP], adst2_s[PP];
  __shared__ float b1_s[PP], b2_s[PP], Wg_s[PP];
  __shared__ float as2_s[NN], ad2_s[NN];
  __shared__ float coef_s[8 * 64 * 4];
  __shared__ float wed_s[8];
  __shared__ float attn_s[NN];

  const int tid = threadIdx.x;
  const int t = blockIdx.x;
  const int wave = tid >> 6, lane = tid & 63;

  // stage inputs
  for (int i = tid; i < NN * FF; i += 512) x_s[i] = x[t * NN * FF + i];
  for (int i = tid; i < FF * PP; i += 512) W1_s[i] = W1[i];
  for (int i = tid; i < EE; i += 512) ea_s[i] = ea_g[t * EE + i];
  if (tid < PP) {
    asrc1_s[tid] = a_src1[tid]; adst1_s[tid] = a_dst1[tid];
    asrc2_s[tid] = a_src2[tid]; adst2_s[tid] = a_dst2[tid];
    b1_s[tid] = b1[tid]; b2_s[tid] = b2[tid]; Wg_s[tid] = Wg[tid];
  }
  if (tid >= 128 && tid < 132) {   // wedot1[h] = sum_c We1[h,c]*a_edge1[h,c]
    const int h = tid - 128;
    float acc = 0.f;
    for (int c = 0; c < 32; ++c) acc += We1[h * 32 + c] * a_edge1[h * 32 + c];
    wed_s[h] = acc;
  }
  if (tid == 132) {                // wedot2 = dot(We2, a_edge2)
    float acc = 0.f;
    for (int c = 0; c < 128; ++c) acc += We2[c] * a_edge2[c];
    wed_s[4] = acc;
  }
  __syncthreads();

  // h1 = x @ W1  -> hA  (8192 outputs, 16/thread)
  {
    const int c = tid & 127, ib = tid >> 7;
    for (int q = 0; q < 16; ++q) {
      const int i = ib * 16 + q;
      float acc = 0.f;
#pragma unroll
      for (int f = 0; f < FF; ++f) acc += x_s[i * FF + f] * W1_s[f * PP + c];
      hA_s[i * PP + c] = acc;
    }
  }
  __syncthreads();

  // per-node attention dots: as1[i][h], ad1[i][h]
  {
    const int half = tid >> 8;          // 0: src dots, 1: dst dots
    const int tt2 = tid & 255;
    const int i = tt2 >> 2, h = tt2 & 3;
    const float* aw = half ? adst1_s : asrc1_s;
    float acc = 0.f;
    for (int cc = 0; cc < 32; ++cc) {
      const int c = (cc + tid) & 31;    // rotation: LDS bank-conflict-free
      acc += hA_s[i * PP + h * 32 + c] * aw[h * 32 + c];
    }
    if (half) ad1_s[i * 4 + h] = acc; else as1_s[i * 4 + h] = acc;
  }
  __syncthreads();

  // GAT1 aggregation: each wave owns dst d = kk*8+wave; lanes 0..62 = srcs
  for (int kk = 0; kk < 8; ++kk) {
    const int d = kk * 8 + wave;
    {
      float a0, a1, a2, a3;
      if (lane < 63) {
        const int s = lane + (lane >= d ? 1 : 0);
        const int j = s * 63 + (d < s ? d : d - 1);
        const float ev = ea_s[j];
        a0 = as1_s[s * 4 + 0] + ad1_s[d * 4 + 0] + ev * wed_s[0];
        a1 = as1_s[s * 4 + 1] + ad1_s[d * 4 + 1] + ev * wed_s[1];
        a2 = as1_s[s * 4 + 2] + ad1_s[d * 4 + 2] + ev * wed_s[2];
        a3 = as1_s[s * 4 + 3] + ad1_s[d * 4 + 3] + ev * wed_s[3];
        a0 = a0 > 0.f ? a0 : 0.2f * a0;
        a1 = a1 > 0.f ? a1 : 0.2f * a1;
        a2 = a2 > 0.f ? a2 : 0.2f * a2;
        a3 = a3 > 0.f ? a3 : 0.2f * a3;
      } else { a0 = a1 = a2 = a3 = -1e30f; }
      const float m0 = wave_max64(a0), m1 = wave_max64(a1);
      const float m2 = wave_max64(a2), m3 = wave_max64(a3);
      const float p0 = (lane < 63) ? __expf(a0 - m0) : 0.f;
      const float p1 = (lane < 63) ? __expf(a1 - m1) : 0.f;
      const float p2 = (lane < 63) ? __expf(a2 - m2) : 0.f;
      const float p3 = (lane < 63) ? __expf(a3 - m3) : 0.f;
      const float s0 = wave_sum64(p0), s1 = wave_sum64(p1);
      const float s2 = wave_sum64(p2), s3 = wave_sum64(p3);
      float* cw = &coef_s[(wave * 64 + lane) * 4];
      cw[0] = p0 / (s0 + 1e-16f);
      cw[1] = p1 / (s1 + 1e-16f);
      cw[2] = p2 / (s2 + 1e-16f);
      cw[3] = p3 / (s3 + 1e-16f);
    }
    __syncthreads();
    {
      const int c0 = lane * 2;
      const int hh = c0 >> 5;
      float acc0 = 0.f, acc1 = 0.f;
      const float* cf = &coef_s[wave * 64 * 4 + hh];
      for (int s = 0; s < 63; ++s) {
        const int sn = s + (s >= d ? 1 : 0);
        const float cv = cf[s * 4];
        const float2 hv = *(const float2*)&hA_s[sn * PP + c0];
        acc0 += cv * hv.x; acc1 += cv * hv.y;
      }
      hB_s[d * PP + c0]     = fmaxf(acc0 + b1_s[c0], 0.f);
      hB_s[d * PP + c0 + 1] = fmaxf(acc1 + b1_s[c0 + 1], 0.f);
    }
    __syncthreads();
  }

  // p2 = relu(gat1) @ W2 -> hA (reuse; h1 dead).  W2 streamed from L2.
  {
    const int c = tid & 127, ib = tid >> 7;
    float acc[16];
#pragma unroll
    for (int q = 0; q < 16; ++q) acc[q] = 0.f;
    for (int f0 = 0; f0 < 128; f0 += 4) {
      const float w0 = W2[(f0 + 0) * PP + c];
      const float w1 = W2[(f0 + 1) * PP + c];
      const float w2 = W2[(f0 + 2) * PP + c];
      const float w3 = W2[(f0 + 3) * PP + c];
#pragma unroll
      for (int q = 0; q < 16; ++q) {
        const float4 hv = *(const float4*)&hB_s[(ib * 16 + q) * PP + f0];
        acc[q] += hv.x * w0 + hv.y * w1 + hv.z * w2 + hv.w * w3;
      }
    }
#pragma unroll
    for (int q = 0; q < 16; ++q) hA_s[(ib * 16 + q) * PP + c] = acc[q];
  }
  __syncthreads();

  // as2/ad2 node dots
  if (tid < 128) {
    const int i = tid >> 1, sel = tid & 1;
    const float* aw = sel ? adst2_s : asrc2_s;
    float acc = 0.f;
    for (int cc = 0; cc < 128; ++cc) {
      const int c = (cc + tid) & 127;
      acc += hA_s[i * PP + c] * aw[c];
    }
    if (sel) ad2_s[i] = acc; else as2_s[i] = acc;
  }
  __syncthreads();

  // GAT2 aggregation (1 head)
  for (int kk = 0; kk < 8; ++kk) {
    const int d = kk * 8 + wave;
    {
      float a;
      if (lane < 63) {
        const int s = lane + (lane >= d ? 1 : 0);
        const int j = s * 63 + (d < s ? d : d - 1);
        a = as2_s[s] + ad2_s[d] + ea_s[j] * wed_s[4];
        a = a > 0.f ? a : 0.2f * a;
      } else a = -1e30f;
      const float m = wave_max64(a);
      const float p = (lane < 63) ? __expf(a - m) : 0.f;
      const float ssum = wave_sum64(p);
      coef_s[wave * 64 + lane] = p / (ssum + 1e-16f);
    }
    __syncthreads();
    {
      const int c0 = lane * 2;
      float acc0 = 0.f, acc1 = 0.f;
      const float* cf = &coef_s[wave * 64];
      for (int s = 0; s < 63; ++s) {
        const int sn = s + (s >= d ? 1 : 0);
        const float cv = cf[s];
        const float2 hv = *(const float2*)&hA_s[sn * PP + c0];
        acc0 += cv * hv.x; acc1 += cv * hv.y;
      }
      hB_s[d * PP + c0]     = fmaxf(acc0 + b2_s[c0], 0.f);
      hB_s[d * PP + c0 + 1] = fmaxf(acc1 + b2_s[c0 + 1], 0.f);
    }
    __syncthreads();
  }

  // attention pooling (softmax over 64 nodes, wave 0) + max pooling
  if (tid < 64) {
    float acc = 0.f;
    for (int cc = 0; cc < 128; ++cc) {
      const int c = (cc + tid) & 127;
      acc += hB_s[tid * PP + c] * Wg_s[c];
    }
    const float logit = acc + bg[0];
    const float m = wave_max64(logit);
    const float p = __expf(logit - m);
    const float ssum = wave_sum64(p);
    attn_s[tid] = p / ssum;
  }
  __syncthreads();
  if (tid < 128) {
    const int c = tid;
    float acc = 0.f, mx = -1e30f;
    for (int i = 0; i < NN; ++i) {
      const float v = hB_s[i * PP + c];
      acc += attn_s[i] * v;
      mx = fmaxf(mx, v);
    }
    embs[t * 256 + c] = acc;
    embs[t * 256 + 128 + c] = mx;
  }
}

// ---------------------------------------------------------------------------
// Z[t][j] = Wih_f[j,:]·embs[t] + bih_f[j] + bhh_f[j]   (blocks 0..255)
// Zb[j]   = Wih_b[j,:]·embs[255] + bih_b[j] + bhh_b[j] (block 256)
// ---------------------------------------------------------------------------
__global__ __launch_bounds__(512, 2)
void zproj_kernel(const float* __restrict__ embs,
                  const float* __restrict__ Wih_f, const float* __restrict__ bih_f,
                  const float* __restrict__ bhh_f,
                  const float* __restrict__ Wih_b, const float* __restrict__ bih_b,
                  const float* __restrict__ bhh_b,
                  float* __restrict__ Z, float* __restrict__ Zb)
{
  __shared__ float e_s[256];
  const int t = blockIdx.x;
  const int j = threadIdx.x;
  const bool bwd = (t == TT);
  const int tsrc = bwd ? (TT - 1) : t;
  if (j < 256) e_s[j] = embs[tsrc * 256 + j];
  __syncthreads();
  const float* W = bwd ? Wih_b : Wih_f;
  float acc = bwd ? (bih_b[j] + bhh_b[j]) : (bih_f[j] + bhh_f[j]);
  const float4* Wr = (const float4*)(W + j * 256);
  const float4* er = (const float4*)e_s;
#pragma unroll 8
  for (int k = 0; k < 64; ++k) {
    const float4 w = Wr[k];
    const float4 e = er[k];
    acc += w.x * e.x + w.y * e.y + w.z * e.z + w.w * e.w;
  }
  if (bwd) Zb[j] = acc; else Z[t * 512 + j] = acc;
}

// ---------------------------------------------------------------------------
// Forward LSTM recurrence (256 steps, single block).
// Round-1 post-mortem: naming the 32 float4s was NOT enough -- LLVM's
// pressure-driven sinking re-loaded them from global every iteration
// (VGPR_Count=88 proved non-residency). Fix: empty `asm volatile` with
// "+v" constraints BEFORE the loop forces the 128 weight floats into
// pinned VGPR tuples for the kernel's lifetime; __launch_bounds__(512,1)
// lifts the allocator budget to 512 VGPRs so there is no pressure excuse.
// ---------------------------------------------------------------------------
__global__ __launch_bounds__(512, 1)
void lstm_kernel(const float* __restrict__ Z, const float* __restrict__ Zb,
                 const float* __restrict__ Whh_f,
                 const float* __restrict__ Wo, const float* __restrict__ bo,
                 float* __restrict__ out)
{
  __shared__ float h_s[128];
  __shared__ float g_s[512];
  __shared__ float hb_s[128];
  __shared__ float red_s[8];
  const int j = threadIdx.x;

  const f32x4* __restrict__ Wr = (const f32x4*)(Whh_f + j * 128);
  f32x4 w0  = Wr[0],  w1  = Wr[1],  w2  = Wr[2],  w3  = Wr[3];
  f32x4 w4  = Wr[4],  w5  = Wr[5],  w6  = Wr[6],  w7  = Wr[7];
  f32x4 w8  = Wr[8],  w9  = Wr[9],  w10 = Wr[10], w11 = Wr[11];
  f32x4 w12 = Wr[12], w13 = Wr[13], w14 = Wr[14], w15 = Wr[15];
  f32x4 w16 = Wr[16], w17 = Wr[17], w18 = Wr[18], w19 = Wr[19];
  f32x4 w20 = Wr[20], w21 = Wr[21], w22 = Wr[22], w23 = Wr[23];
  f32x4 w24 = Wr[24], w25 = Wr[25], w26 = Wr[26], w27 = Wr[27];
  f32x4 w28 = Wr[28], w29 = Wr[29], w30 = Wr[30], w31 = Wr[31];
  // Pin: loads must complete before these (data dep), and the volatile asm
  // cannot be sunk into the loop -> weights stay VGPR-resident.
  asm volatile("" : "+v"(w0), "+v"(w1), "+v"(w2), "+v"(w3),
                    "+v"(w4), "+v"(w5), "+v"(w6), "+v"(w7));
  asm volatile("" : "+v"(w8), "+v"(w9), "+v"(w10), "+v"(w11),
                    "+v"(w12), "+v"(w13), "+v"(w14), "+v"(w15));
  asm volatile("" : "+v"(w16), "+v"(w17), "+v"(w18), "+v"(w19),
                    "+v"(w20), "+v"(w21), "+v"(w22), "+v"(w23));
  asm volatile("" : "+v"(w24), "+v"(w25), "+v"(w26), "+v"(w27),
                    "+v"(w28), "+v"(w29), "+v"(w30), "+v"(w31));

  float c = 0.f;
  if (j < 128) h_s[j] = 0.f;
  __syncthreads();

  float zcur = Z[j];
  const f32x4* hr = (const f32x4*)h_s;
  for (int t = 0; t < TT; ++t) {
    const float znext = (t < TT - 1) ? Z[(t + 1) * 512 + j] : 0.f;  // prefetch
    float a0 = zcur, a1 = 0.f, a2 = 0.f, a3 = 0.f;
#define ACCK(k, A) { const f32x4 hv = hr[k]; \
    A = fmaf(hv.x, w##k.x, A); A = fmaf(hv.y, w##k.y, A); \
    A = fmaf(hv.z, w##k.z, A); A = fmaf(hv.w, w##k.w, A); }
    ACCK(0, a0)  ACCK(1, a1)  ACCK(2, a2)  ACCK(3, a3)
    ACCK(4, a0)  ACCK(5, a1)  ACCK(6, a2)  ACCK(7, a3)
    ACCK(8, a0)  ACCK(9, a1)  ACCK(10, a2) ACCK(11, a3)
    ACCK(12, a0) ACCK(13, a1) ACCK(14, a2) ACCK(15, a3)
    ACCK(16, a0) ACCK(17, a1) ACCK(18, a2) ACCK(19, a3)
    ACCK(20, a0) ACCK(21, a1) ACCK(22, a2) ACCK(23, a3)
    ACCK(24, a0) ACCK(25, a1) ACCK(26, a2) ACCK(27, a3)
    ACCK(28, a0) ACCK(29, a1) ACCK(30, a2) ACCK(31, a3)
#undef ACCK
    g_s[j] = (a0 + a1) + (a2 + a3);
    __syncthreads();
    if (j < 128) {
      const float gi = g_s[j], gf = g_s[128 + j], gg = g_s[256 + j], go = g_s[384 + j];
      c = sigm(gf) * c + sigm(gi) * tanh_fast(gg);
      h_s[j] = sigm(go) * tanh_fast(c);
    }
    __syncthreads();
    zcur = znext;
  }

  // backward LSTM, first step only (h=c=0): elementwise on Zb
  if (j < 128) {
    const float gi = Zb[j], gg = Zb[256 + j], go = Zb[384 + j];
    const float cb = sigm(gi) * tanh_fast(gg);
    hb_s[j] = sigm(go) * tanh_fast(cb);
  }
  __syncthreads();

  // out = sigmoid(concat(h_f, h_b) · Wo + bo)
  float v = 0.f;
  if (j < 128) v = h_s[j] * Wo[j];
  else if (j < 256) v = hb_s[j - 128] * Wo[j];
  v = wave_sum64(v);
  if ((j & 63) == 0) red_s[j >> 6] = v;
  __syncthreads();
  if (j == 0) {
    float s = bo[0];
#pragma unroll
    for (int k = 0; k < 8; ++k) s += red_s[k];
    out[0] = 1.f / (1.f + __expf(-s));
  }
}

extern "C" void kernel_launch(void* const* d_in, const int* in_sizes, int n_in,
                              void* d_out, int out_size, void* d_ws, size_t ws_size,
                              hipStream_t stream) {
  const float* x       = (const float*)d_in[0];
  // d_in[1] = edge_index (int32) — complete digraph, indexed analytically
  const float* ea      = (const float*)d_in[2];
  const float* W1      = (const float*)d_in[3];
  const float* a_src1  = (const float*)d_in[4];
  const float* a_dst1  = (const float*)d_in[5];
  const float* We1     = (const float*)d_in[6];
  const float* a_edge1 = (const float*)d_in[7];
  const float* b1      = (const float*)d_in[8];
  const float* W2      = (const float*)d_in[9];
  const float* a_src2  = (const float*)d_in[10];
  const float* a_dst2  = (const float*)d_in[11];
  const float* We2     = (const float*)d_in[12];
  const float* a_edge2 = (const float*)d_in[13];
  const float* b2      = (const float*)d_in[14];
  const float* Wg      = (const float*)d_in[15];
  const float* bg      = (const float*)d_in[16];
  const float* Wih_f   = (const float*)d_in[17];
  const float* Whh_f   = (const float*)d_in[18];
  const float* bih_f   = (const float*)d_in[19];
  const float* bhh_f   = (const float*)d_in[20];
  const float* Wih_b   = (const float*)d_in[21];
  // d_in[22] = Whh_b — unused: backward LSTM contributes only its first step (h=0)
  const float* bih_b   = (const float*)d_in[23];
  const float* bhh_b   = (const float*)d_in[24];
  const float* Wo      = (const float*)d_in[25];
  const float* bo      = (const float*)d_in[26];
  float* out = (float*)d_out;

  float* embs = (float*)d_ws;            // 256*256 floats
  float* Z    = embs + 256 * 256;        // 256*512 floats
  float* Zb   = Z + 256 * 512;           // 512 floats

  gnn_kernel<<<256, 512, 0, stream>>>(x, ea, W1, a_src1, a_dst1, We1, a_edge1, b1,
                                      W2, a_src2, a_dst2, We2, a_edge2, b2, Wg, bg, embs);
  zproj_kernel<<<257, 512, 0, stream>>>(embs, Wih_f, bih_f, bhh_f, Wih_b, bih_b, bhh_b, Z, Zb);
  lstm_kernel<<<1, 512, 0, stream>>>(Z, Zb, Whh_f, Wo, bo, out);
}

// Round 4
// 352.793 us; speedup vs baseline: 1.2603x; 1.0717x over previous
//
#include <hip/hip_runtime.h>
#include <math.h>

#define NN 64      // nodes
#define TT 256     // frames
#define FF 13      // input features
#define EE 4032    // edges (complete digraph)
#define PP 128     // pooling channels / GAT1 out
#define HH 128     // hidden

typedef float f32x4 __attribute__((ext_vector_type(4)));

__device__ __forceinline__ float wave_max64(float v) {
#pragma unroll
  for (int off = 32; off > 0; off >>= 1) v = fmaxf(v, __shfl_xor(v, off, 64));
  return v;
}
__device__ __forceinline__ float wave_sum64(float v) {
#pragma unroll
  for (int off = 32; off > 0; off >>= 1) v += __shfl_xor(v, off, 64);
  return v;
}
__device__ __forceinline__ float sigm(float x) { return 1.f / (1.f + __expf(-x)); }
__device__ __forceinline__ float tanh_fast(float x) { return 1.f - 2.f / (__expf(2.f * x) + 1.f); }

// ---------------------------------------------------------------------------
// Per-frame GNN: GAT1 (4 heads) -> relu -> GAT2 (1 head) -> relu ->
// attention-pool + max-pool -> embs[t][256]
// One block per frame, 512 threads (8 waves). Complete-graph edge indexing:
// edge (s->d) has id j = s*63 + (d<s ? d : d-1)  [np.nonzero(~eye) order].
// ---------------------------------------------------------------------------
__global__ __launch_bounds__(512, 2)
void gnn_kernel(const float* __restrict__ x, const float* __restrict__ ea_g,
                const float* __restrict__ W1, const float* __restrict__ a_src1,
                const float* __restrict__ a_dst1, const float* __restrict__ We1,
                const float* __restrict__ a_edge1, const float* __restrict__ b1,
                const float* __restrict__ W2, const float* __restrict__ a_src2,
                const float* __restrict__ a_dst2, const float* __restrict__ We2,
                const float* __restrict__ a_edge2, const float* __restrict__ b2,
                const float* __restrict__ Wg, const float* __restrict__ bg,
                float* __restrict__ embs)
{
  __shared__ float x_s[NN * FF];
  __shared__ float W1_s[FF * PP];
  __shared__ float ea_s[EE];
  __shared__ float hA_s[NN * PP];   // h1 (GAT1 projected), later p2 (GAT2 projected)
  __shared__ float hB_s[NN * PP];   // relu(GAT1 out), later relu(GAT2 out)
  __shared__ float as1_s[NN * 4];
  __shared__ float ad1_s[NN * 4];
  __shared__ float asrc1_s[PP], adst1_s[PP], asrc2_s[PP], adst2_s[PP];
  __shared__ float b1_s[PP], b2_s[PP], Wg_s[PP];
  __shared__ float as2_s[NN], ad2_s[NN];
  __shared__ float coef_s[8 * 64 * 4];
  __shared__ float wed_s[8];
  __shared__ float attn_s[NN];

  const int tid = threadIdx.x;
  const int t = blockIdx.x;
  const int wave = tid >> 6, lane = tid & 63;

  // stage inputs
  for (int i = tid; i < NN * FF; i += 512) x_s[i] = x[t * NN * FF + i];
  for (int i = tid; i < FF * PP; i += 512) W1_s[i] = W1[i];
  for (int i = tid; i < EE; i += 512) ea_s[i] = ea_g[t * EE + i];
  if (tid < PP) {
    asrc1_s[tid] = a_src1[tid]; adst1_s[tid] = a_dst1[tid];
    asrc2_s[tid] = a_src2[tid]; adst2_s[tid] = a_dst2[tid];
    b1_s[tid] = b1[tid]; b2_s[tid] = b2[tid]; Wg_s[tid] = Wg[tid];
  }
  if (tid >= 128 && tid < 132) {   // wedot1[h] = sum_c We1[h,c]*a_edge1[h,c]
    const int h = tid - 128;
    float acc = 0.f;
    for (int c = 0; c < 32; ++c) acc += We1[h * 32 + c] * a_edge1[h * 32 + c];
    wed_s[h] = acc;
  }
  if (tid == 132) {                // wedot2 = dot(We2, a_edge2)
    float acc = 0.f;
    for (int c = 0; c < 128; ++c) acc += We2[c] * a_edge2[c];
    wed_s[4] = acc;
  }
  __syncthreads();

  // h1 = x @ W1  -> hA  (8192 outputs, 16/thread)
  {
    const int c = tid & 127, ib = tid >> 7;
    for (int q = 0; q < 16; ++q) {
      const int i = ib * 16 + q;
      float acc = 0.f;
#pragma unroll
      for (int f = 0; f < FF; ++f) acc += x_s[i * FF + f] * W1_s[f * PP + c];
      hA_s[i * PP + c] = acc;
    }
  }
  __syncthreads();

  // per-node attention dots: as1[i][h], ad1[i][h]
  {
    const int half = tid >> 8;          // 0: src dots, 1: dst dots
    const int tt2 = tid & 255;
    const int i = tt2 >> 2, h = tt2 & 3;
    const float* aw = half ? adst1_s : asrc1_s;
    float acc = 0.f;
    for (int cc = 0; cc < 32; ++cc) {
      const int c = (cc + tid) & 31;    // rotation: LDS bank-conflict-free
      acc += hA_s[i * PP + h * 32 + c] * aw[h * 32 + c];
    }
    if (half) ad1_s[i * 4 + h] = acc; else as1_s[i * 4 + h] = acc;
  }
  __syncthreads();

  // GAT1 aggregation: each wave owns dst d = kk*8+wave; lanes 0..62 = srcs
  for (int kk = 0; kk < 8; ++kk) {
    const int d = kk * 8 + wave;
    {
      float a0, a1, a2, a3;
      if (lane < 63) {
        const int s = lane + (lane >= d ? 1 : 0);
        const int j = s * 63 + (d < s ? d : d - 1);
        const float ev = ea_s[j];
        a0 = as1_s[s * 4 + 0] + ad1_s[d * 4 + 0] + ev * wed_s[0];
        a1 = as1_s[s * 4 + 1] + ad1_s[d * 4 + 1] + ev * wed_s[1];
        a2 = as1_s[s * 4 + 2] + ad1_s[d * 4 + 2] + ev * wed_s[2];
        a3 = as1_s[s * 4 + 3] + ad1_s[d * 4 + 3] + ev * wed_s[3];
        a0 = a0 > 0.f ? a0 : 0.2f * a0;
        a1 = a1 > 0.f ? a1 : 0.2f * a1;
        a2 = a2 > 0.f ? a2 : 0.2f * a2;
        a3 = a3 > 0.f ? a3 : 0.2f * a3;
      } else { a0 = a1 = a2 = a3 = -1e30f; }
      const float m0 = wave_max64(a0), m1 = wave_max64(a1);
      const float m2 = wave_max64(a2), m3 = wave_max64(a3);
      const float p0 = (lane < 63) ? __expf(a0 - m0) : 0.f;
      const float p1 = (lane < 63) ? __expf(a1 - m1) : 0.f;
      const float p2 = (lane < 63) ? __expf(a2 - m2) : 0.f;
      const float p3 = (lane < 63) ? __expf(a3 - m3) : 0.f;
      const float s0 = wave_sum64(p0), s1 = wave_sum64(p1);
      const float s2 = wave_sum64(p2), s3 = wave_sum64(p3);
      float* cw = &coef_s[(wave * 64 + lane) * 4];
      cw[0] = p0 / (s0 + 1e-16f);
      cw[1] = p1 / (s1 + 1e-16f);
      cw[2] = p2 / (s2 + 1e-16f);
      cw[3] = p3 / (s3 + 1e-16f);
    }
    __syncthreads();
    {
      const int c0 = lane * 2;
      const int hh = c0 >> 5;
      float acc0 = 0.f, acc1 = 0.f;
      const float* cf = &coef_s[wave * 64 * 4 + hh];
      for (int s = 0; s < 63; ++s) {
        const int sn = s + (s >= d ? 1 : 0);
        const float cv = cf[s * 4];
        const float2 hv = *(const float2*)&hA_s[sn * PP + c0];
        acc0 += cv * hv.x; acc1 += cv * hv.y;
      }
      hB_s[d * PP + c0]     = fmaxf(acc0 + b1_s[c0], 0.f);
      hB_s[d * PP + c0 + 1] = fmaxf(acc1 + b1_s[c0 + 1], 0.f);
    }
    __syncthreads();
  }

  // p2 = relu(gat1) @ W2 -> hA (reuse; h1 dead).  W2 streamed from L2.
  {
    const int c = tid & 127, ib = tid >> 7;
    float acc[16];
#pragma unroll
    for (int q = 0; q < 16; ++q) acc[q] = 0.f;
    for (int f0 = 0; f0 < 128; f0 += 4) {
      const float w0 = W2[(f0 + 0) * PP + c];
      const float w1 = W2[(f0 + 1) * PP + c];
      const float w2 = W2[(f0 + 2) * PP + c];
      const float w3 = W2[(f0 + 3) * PP + c];
#pragma unroll
      for (int q = 0; q < 16; ++q) {
        const float4 hv = *(const float4*)&hB_s[(ib * 16 + q) * PP + f0];
        acc[q] += hv.x * w0 + hv.y * w1 + hv.z * w2 + hv.w * w3;
      }
    }
#pragma unroll
    for (int q = 0; q < 16; ++q) hA_s[(ib * 16 + q) * PP + c] = acc[q];
  }
  __syncthreads();

  // as2/ad2 node dots
  if (tid < 128) {
    const int i = tid >> 1, sel = tid & 1;
    const float* aw = sel ? adst2_s : asrc2_s;
    float acc = 0.f;
    for (int cc = 0; cc < 128; ++cc) {
      const int c = (cc + tid) & 127;
      acc += hA_s[i * PP + c] * aw[c];
    }
    if (sel) ad2_s[i] = acc; else as2_s[i] = acc;
  }
  __syncthreads();

  // GAT2 aggregation (1 head)
  for (int kk = 0; kk < 8; ++kk) {
    const int d = kk * 8 + wave;
    {
      float a;
      if (lane < 63) {
        const int s = lane + (lane >= d ? 1 : 0);
        const int j = s * 63 + (d < s ? d : d - 1);
        a = as2_s[s] + ad2_s[d] + ea_s[j] * wed_s[4];
        a = a > 0.f ? a : 0.2f * a;
      } else a = -1e30f;
      const float m = wave_max64(a);
      const float p = (lane < 63) ? __expf(a - m) : 0.f;
      const float ssum = wave_sum64(p);
      coef_s[wave * 64 + lane] = p / (ssum + 1e-16f);
    }
    __syncthreads();
    {
      const int c0 = lane * 2;
      float acc0 = 0.f, acc1 = 0.f;
      const float* cf = &coef_s[wave * 64];
      for (int s = 0; s < 63; ++s) {
        const int sn = s + (s >= d ? 1 : 0);
        const float cv = cf[s];
        const float2 hv = *(const float2*)&hA_s[sn * PP + c0];
        acc0 += cv * hv.x; acc1 += cv * hv.y;
      }
      hB_s[d * PP + c0]     = fmaxf(acc0 + b2_s[c0], 0.f);
      hB_s[d * PP + c0 + 1] = fmaxf(acc1 + b2_s[c0 + 1], 0.f);
    }
    __syncthreads();
  }

  // attention pooling (softmax over 64 nodes, wave 0) + max pooling
  if (tid < 64) {
    float acc = 0.f;
    for (int cc = 0; cc < 128; ++cc) {
      const int c = (cc + tid) & 127;
      acc += hB_s[tid * PP + c] * Wg_s[c];
    }
    const float logit = acc + bg[0];
    const float m = wave_max64(logit);
    const float p = __expf(logit - m);
    const float ssum = wave_sum64(p);
    attn_s[tid] = p / ssum;
  }
  __syncthreads();
  if (tid < 128) {
    const int c = tid;
    float acc = 0.f, mx = -1e30f;
    for (int i = 0; i < NN; ++i) {
      const float v = hB_s[i * PP + c];
      acc += attn_s[i] * v;
      mx = fmaxf(mx, v);
    }
    embs[t * 256 + c] = acc;
    embs[t * 256 + 128 + c] = mx;
  }
}

// ---------------------------------------------------------------------------
// Z[t][j] = Wih_f[j,:]·embs[t] + bih_f[j] + bhh_f[j]   (blocks 0..255)
// Zb[j]   = Wih_b[j,:]·embs[255] + bih_b[j] + bhh_b[j] (block 256)
// ---------------------------------------------------------------------------
__global__ __launch_bounds__(512, 2)
void zproj_kernel(const float* __restrict__ embs,
                  const float* __restrict__ Wih_f, const float* __restrict__ bih_f,
                  const float* __restrict__ bhh_f,
                  const float* __restrict__ Wih_b, const float* __restrict__ bih_b,
                  const float* __restrict__ bhh_b,
                  float* __restrict__ Z, float* __restrict__ Zb)
{
  __shared__ float e_s[256];
  const int t = blockIdx.x;
  const int j = threadIdx.x;
  const bool bwd = (t == TT);
  const int tsrc = bwd ? (TT - 1) : t;
  if (j < 256) e_s[j] = embs[tsrc * 256 + j];
  __syncthreads();
  const float* W = bwd ? Wih_b : Wih_f;
  float acc = bwd ? (bih_b[j] + bhh_b[j]) : (bih_f[j] + bhh_f[j]);
  const float4* Wr = (const float4*)(W + j * 256);
  const float4* er = (const float4*)e_s;
#pragma unroll 8
  for (int k = 0; k < 64; ++k) {
    const float4 w = Wr[k];
    const float4 e = er[k];
    acc += w.x * e.x + w.y * e.y + w.z * e.z + w.w * e.w;
  }
  if (bwd) Zb[j] = acc; else Z[t * 512 + j] = acc;
}

// ---------------------------------------------------------------------------
// Forward LSTM recurrence (256 steps, single block of 1024 threads).
// R2/R3 post-mortem: 512 threads x 128 weight floats (=190 VGPR demand) lost
// the register-allocator fight every way we phrased it (VGPR_Count stuck at
// 88 => weights in scratch). Structural fix: split-k across 2 thread groups:
// thread (j = tid&511, s = tid>>9) holds HALF a Whh row = 64 floats =
// 16 f32x4 = 64 VGPRs; demand ~95 < 128-VGPR budget at the mandatory
// 4 waves/SIMD, so no spill pressure exists. Single keep-alive asm (all 16
// operands in ONE statement) blocks load-sinking without leaving a
// spill-between-pins hole. Partials combine through LDS p_s[1024].
// ---------------------------------------------------------------------------
__global__ __launch_bounds__(1024, 4)
void lstm_kernel(const float* __restrict__ Z, const float* __restrict__ Zb,
                 const float* __restrict__ Whh_f,
                 const float* __restrict__ Wo, const float* __restrict__ bo,
                 float* __restrict__ out)
{
  __shared__ float h_s[128];
  __shared__ float p_s[1024];
  __shared__ float hb_s[128];
  __shared__ float red_s[16];
  const int tid = threadIdx.x;
  const int j = tid & 511;     // gate index
  const int s = tid >> 9;      // k-half (0: h[0..63], 1: h[64..127])

  const f32x4* __restrict__ Wr = (const f32x4*)(Whh_f + j * 128 + s * 64);
  f32x4 w0  = Wr[0],  w1  = Wr[1],  w2  = Wr[2],  w3  = Wr[3];
  f32x4 w4  = Wr[4],  w5  = Wr[5],  w6  = Wr[6],  w7  = Wr[7];
  f32x4 w8  = Wr[8],  w9  = Wr[9],  w10 = Wr[10], w11 = Wr[11];
  f32x4 w12 = Wr[12], w13 = Wr[13], w14 = Wr[14], w15 = Wr[15];
  asm volatile("" : "+v"(w0), "+v"(w1), "+v"(w2),  "+v"(w3),
                    "+v"(w4), "+v"(w5), "+v"(w6),  "+v"(w7),
                    "+v"(w8), "+v"(w9), "+v"(w10), "+v"(w11),
                    "+v"(w12), "+v"(w13), "+v"(w14), "+v"(w15));

  float c = 0.f;
  if (tid < 128) h_s[tid] = 0.f;
  __syncthreads();

  float zcur = (s == 0) ? Z[j] : 0.f;   // bias (bih+bhh) folded into Z
  const f32x4* hr = (const f32x4*)h_s + s * 16;
  for (int t = 0; t < TT; ++t) {
    const float znext = (s == 0 && t < TT - 1) ? Z[(t + 1) * 512 + j] : 0.f;
    float a0 = zcur, a1 = 0.f, a2 = 0.f, a3 = 0.f;
#define ACCK(k, A) { const f32x4 hv = hr[k]; \
    A = fmaf(hv.x, w##k.x, A); A = fmaf(hv.y, w##k.y, A); \
    A = fmaf(hv.z, w##k.z, A); A = fmaf(hv.w, w##k.w, A); }
    ACCK(0, a0)  ACCK(1, a1)  ACCK(2, a2)  ACCK(3, a3)
    ACCK(4, a0)  ACCK(5, a1)  ACCK(6, a2)  ACCK(7, a3)
    ACCK(8, a0)  ACCK(9, a1)  ACCK(10, a2) ACCK(11, a3)
    ACCK(12, a0) ACCK(13, a1) ACCK(14, a2) ACCK(15, a3)
#undef ACCK
    p_s[tid] = (a0 + a1) + (a2 + a3);
    __syncthreads();
    if (tid < 128) {
      const float gi = p_s[tid]       + p_s[512 + tid];
      const float gf = p_s[128 + tid] + p_s[640 + tid];
      const float gg = p_s[256 + tid] + p_s[768 + tid];
      const float go = p_s[384 + tid] + p_s[896 + tid];
      c = sigm(gf) * c + sigm(gi) * tanh_fast(gg);
      h_s[tid] = sigm(go) * tanh_fast(c);
    }
    __syncthreads();
    zcur = znext;
  }

  // backward LSTM, first step only (h=c=0): elementwise on Zb
  if (tid < 128) {
    const float gi = Zb[tid], gg = Zb[256 + tid], go = Zb[384 + tid];
    const float cb = sigm(gi) * tanh_fast(gg);
    hb_s[tid] = sigm(go) * tanh_fast(cb);
  }
  __syncthreads();

  // out = sigmoid(concat(h_f, h_b) · Wo + bo)
  float v = 0.f;
  if (tid < 128) v = h_s[tid] * Wo[tid];
  else if (tid < 256) v = hb_s[tid - 128] * Wo[tid];
  v = wave_sum64(v);
  if ((tid & 63) == 0) red_s[tid >> 6] = v;
  __syncthreads();
  if (tid == 0) {
    float sum = bo[0];
#pragma unroll
    for (int k = 0; k < 16; ++k) sum += red_s[k];
    out[0] = 1.f / (1.f + __expf(-sum));
  }
}

extern "C" void kernel_launch(void* const* d_in, const int* in_sizes, int n_in,
                              void* d_out, int out_size, void* d_ws, size_t ws_size,
                              hipStream_t stream) {
  const float* x       = (const float*)d_in[0];
  // d_in[1] = edge_index (int32) — complete digraph, indexed analytically
  const float* ea      = (const float*)d_in[2];
  const float* W1      = (const float*)d_in[3];
  const float* a_src1  = (const float*)d_in[4];
  const float* a_dst1  = (const float*)d_in[5];
  const float* We1     = (const float*)d_in[6];
  const float* a_edge1 = (const float*)d_in[7];
  const float* b1      = (const float*)d_in[8];
  const float* W2      = (const float*)d_in[9];
  const float* a_src2  = (const float*)d_in[10];
  const float* a_dst2  = (const float*)d_in[11];
  const float* We2     = (const float*)d_in[12];
  const float* a_edge2 = (const float*)d_in[13];
  const float* b2      = (const float*)d_in[14];
  const float* Wg      = (const float*)d_in[15];
  const float* bg      = (const float*)d_in[16];
  const float* Wih_f   = (const float*)d_in[17];
  const float* Whh_f   = (const float*)d_in[18];
  const float* bih_f   = (const float*)d_in[19];
  const float* bhh_f   = (const float*)d_in[20];
  const float* Wih_b   = (const float*)d_in[21];
  // d_in[22] = Whh_b — unused: backward LSTM contributes only its first step (h=0)
  const float* bih_b   = (const float*)d_in[23];
  const float* bhh_b   = (const float*)d_in[24];
  const float* Wo      = (const float*)d_in[25];
  const float* bo      = (const float*)d_in[26];
  float* out = (float*)d_out;

  float* embs = (float*)d_ws;            // 256*256 floats
  float* Z    = embs + 256 * 256;        // 256*512 floats
  float* Zb   = Z + 256 * 512;           // 512 floats

  gnn_kernel<<<256, 512, 0, stream>>>(x, ea, W1, a_src1, a_dst1, We1, a_edge1, b1,
                                      W2, a_src2, a_dst2, We2, a_edge2, b2, Wg, bg, embs);
  zproj_kernel<<<257, 512, 0, stream>>>(embs, Wih_f, bih_f, bhh_f, Wih_b, bih_b, bhh_b, Z, Zb);
  lstm_kernel<<<1, 1024, 0, stream>>>(Z, Zb, Whh_f, Wo, bo, out);
}